// Round 1
// baseline (259.536 us; speedup 1.0000x reference)
//
#include <hip/hip_runtime.h>
#include <stdint.h>

// ---------------------------------------------------------------------------
// AttentionHead: out = softmax_causal((Xq WQ)(Xk WK)^T / sqrt(D)) (Xv WV)
// B=4, S=2048, D=1024.  All heavy math in bf16 MFMA (f32 accum).
// Pipeline:
//   1. cvt:     Xq,Xk,Xv f32 -> bf16
//   2. wtrans:  WQ,WK,WV f32 -> bf16 transposed (WT[e][k]=W[k][e]); 1/32 folded into WQT
//   3. gemm_bt: Q = Xq*WQT^T, K = Xk*WKT^T   (B^T-layout GEMM, bf16 out)
//               VT = WVT*Xv^T  -> V transposed [1024][8192]
//   4. gemm_bt: S_b = Q_b K_b^T  (bf16 out, skip blocks above diagonal)
//   5. softmax: in-place causal softmax rows (reads k<=q, zero-fills to 128 bdy)
//   6. gemm_bt: out_b = P_b V_b  (f32 out, K-loop clamped to (bm+1)*128)
// Workspace (bf16 elems): [Xq|Xk|Xv|Q|K|VT] 6x2^23 + 3x2^20 weights = 107 MB;
// scores/P (2^24 elems) alias Xq+Xk which are dead by then.
// ---------------------------------------------------------------------------

typedef __attribute__((ext_vector_type(8))) short short8;
typedef __attribute__((ext_vector_type(8))) unsigned short ushort8;
typedef __attribute__((ext_vector_type(4))) float f32x4;

__device__ __forceinline__ unsigned short f2bf(float f) {
  union { float f; unsigned u; } v; v.f = f;
  unsigned u = v.u + 0x7FFFu + ((v.u >> 16) & 1u);   // RNE
  return (unsigned short)(u >> 16);
}
__device__ __forceinline__ float bf2f(unsigned short h) {
  union { unsigned u; float f; } v; v.u = ((unsigned)h) << 16;
  return v.f;
}

__device__ __forceinline__ void gload16(const void* g, void* l) {
  __builtin_amdgcn_global_load_lds(
      (const __attribute__((address_space(1))) unsigned int*)g,
      (__attribute__((address_space(3))) unsigned int*)l, 16, 0, 0);
}

// ---------------- f32 -> bf16 convert (8 elems/thread) ----------------------
__global__ __launch_bounds__(256)
void cvt_bf16(const float* __restrict__ in, unsigned short* __restrict__ out, long n) {
  const long i = ((long)blockIdx.x * 256 + threadIdx.x) * 8;
  if (i >= n) return;
  float4 a = *(const float4*)(in + i);
  float4 b = *(const float4*)(in + i + 4);
  ushort8 r;
  r[0] = f2bf(a.x); r[1] = f2bf(a.y); r[2] = f2bf(a.z); r[3] = f2bf(a.w);
  r[4] = f2bf(b.x); r[5] = f2bf(b.y); r[6] = f2bf(b.z); r[7] = f2bf(b.w);
  *(ushort8*)(out + i) = r;
}

// ---------------- weight transpose: WT[e][k] = W[k][e]*scale ----------------
__global__ __launch_bounds__(256)
void wtrans(const float* __restrict__ W, unsigned short* __restrict__ WT, float scale) {
  __shared__ float t[32][33];
  const int bk = blockIdx.x * 32;   // k base
  const int be = blockIdx.y * 32;   // e base
  const int tx = threadIdx.x, ty = threadIdx.y;  // (32,8)
#pragma unroll
  for (int j = 0; j < 32; j += 8)
    t[ty + j][tx] = W[(long)(bk + ty + j) * 1024 + (be + tx)];
  __syncthreads();
#pragma unroll
  for (int j = 0; j < 32; j += 8)
    WT[(long)(be + ty + j) * 1024 + (bk + tx)] = f2bf(t[tx][ty + j] * scale);
}

// ---------------- B^T-layout bf16 GEMM, m97 structure -----------------------
// C[m][n] = sum_k A[m][k] * B[n][k];  M,N mult of 128, K mult of 32.
template<typename CT, bool CAUSAL_SKIP, bool KCLAMP>
__global__ __launch_bounds__(256)
void gemm_bt(const unsigned short* __restrict__ Ag,
             const unsigned short* __restrict__ Bg,
             CT* __restrict__ Cg,
             int M, int N, int K, int lda, int ldb, int ldc,
             long sA, long sB, long sC) {
  const int bn = blockIdx.x, bm = blockIdx.y, bz = blockIdx.z;
  if (CAUSAL_SKIP && bn > bm) return;   // fully-masked tile: never read
  const unsigned short* A = Ag + (long)bz * sA;
  const unsigned short* B = Bg + (long)bz * sB;
  CT* C = Cg + (long)bz * sC;

  __shared__ __align__(16) unsigned short Al[128 * 32];
  __shared__ __align__(16) unsigned short Bl[128 * 32];

  const int tid = threadIdx.x;
  const int lane = tid & 63;
  const int wid = tid >> 6;
  const int wr = wid >> 1, wc = wid & 1;        // wave owns 64x64 at (wr,wc)
  const int srow = tid >> 2;                    // staging row (t/4)
  const int scol = (tid & 3) << 3;              // staging col8
  const int fr = lane & 15;                     // frag row/col within 16
  const int fq = lane >> 4;                     // k-chunk of 8
  const int m0 = bm * 128, n0 = bn * 128;
  const int kmax = KCLAMP ? min(K, (bm + 1) * 128) : K;

  f32x4 acc[4][4] = {};

  const unsigned short* Aps = A + (long)(m0 + srow) * lda + scol;
  const unsigned short* Bps = B + (long)(n0 + srow) * ldb + scol;
  unsigned short* Ald = &Al[srow * 32 + scol];
  unsigned short* Bld = &Bl[srow * 32 + scol];
  const long a64 = 64L * lda, b64 = 64L * ldb;

  for (int k0 = 0; k0 < kmax; k0 += 32) {
    gload16(Aps + k0,        Ald);
    gload16(Aps + a64 + k0,  Ald + 64 * 32);
    gload16(Bps + k0,        Bld);
    gload16(Bps + b64 + k0,  Bld + 64 * 32);
    __syncthreads();
    short8 af[4], bfr[4];
#pragma unroll
    for (int m = 0; m < 4; ++m)
      af[m] = *(const short8*)&Al[(wr * 64 + m * 16 + fr) * 32 + fq * 8];
#pragma unroll
    for (int n = 0; n < 4; ++n)
      bfr[n] = *(const short8*)&Bl[(wc * 64 + n * 16 + fr) * 32 + fq * 8];
#pragma unroll
    for (int m = 0; m < 4; ++m)
#pragma unroll
      for (int n = 0; n < 4; ++n)
        acc[m][n] = __builtin_amdgcn_mfma_f32_16x16x32_bf16(af[m], bfr[n], acc[m][n], 0, 0, 0);
    __syncthreads();
  }

  // C/D layout (verified m89/m91): col = lane&15, row = (lane>>4)*4 + reg
#pragma unroll
  for (int m = 0; m < 4; ++m) {
    const int row = m0 + wr * 64 + m * 16 + fq * 4;
#pragma unroll
    for (int n = 0; n < 4; ++n) {
      const int col = n0 + wc * 64 + n * 16 + fr;
#pragma unroll
      for (int r = 0; r < 4; ++r) {
        float v = acc[m][n][r];
        if constexpr (sizeof(CT) == 2)
          C[(long)(row + r) * ldc + col] = (CT)f2bf(v);
        else
          C[(long)(row + r) * ldc + col] = (CT)v;
      }
    }
  }
}

// ---------------- causal softmax, in place over bf16 rows -------------------
__global__ __launch_bounds__(256)
void softmax_causal(unsigned short* __restrict__ P) {
  const int row = blockIdx.x;              // b*2048 + q
  const int q = row & 2047;
  unsigned short* p = P + (long)row * 2048;
  const int n = q + 1;                     // valid length
  const int nfill = ((q >> 7) + 1) << 7;   // PV reads up to this 128-boundary
  __shared__ float buf[2048];
  __shared__ float redm[4], reds[4];
  const int tid = threadIdx.x;
  const int lane = tid & 63, wid = tid >> 6;

  float lmax = -3.0e38f;
  for (int i = tid; i < n; i += 256) {
    float v = bf2f(p[i]);
    buf[i] = v;
    lmax = fmaxf(lmax, v);
  }
#pragma unroll
  for (int off = 1; off < 64; off <<= 1)
    lmax = fmaxf(lmax, __shfl_xor(lmax, off));
  if (lane == 0) redm[wid] = lmax;
  __syncthreads();
  const float mx = fmaxf(fmaxf(redm[0], redm[1]), fmaxf(redm[2], redm[3]));

  float lsum = 0.f;
  for (int i = tid; i < n; i += 256) {
    float e = __expf(buf[i] - mx);
    buf[i] = e;
    lsum += e;
  }
#pragma unroll
  for (int off = 1; off < 64; off <<= 1)
    lsum += __shfl_xor(lsum, off);
  if (lane == 0) reds[wid] = lsum;
  __syncthreads();
  const float inv = 1.0f / (reds[0] + reds[1] + reds[2] + reds[3]);

  for (int i = tid; i < n; i += 256) p[i] = f2bf(buf[i] * inv);
  for (int i = n + tid; i < nfill; i += 256) p[i] = 0;   // zeros PV will read
}

// ---------------------------------------------------------------------------
extern "C" void kernel_launch(void* const* d_in, const int* in_sizes, int n_in,
                              void* d_out, int out_size, void* d_ws, size_t ws_size,
                              hipStream_t stream) {
  const float* Xk = (const float*)d_in[0];
  const float* Xv = (const float*)d_in[1];
  const float* Xq = (const float*)d_in[2];
  const float* WK = (const float*)d_in[3];
  const float* WQ = (const float*)d_in[4];
  const float* WV = (const float*)d_in[5];
  float* out = (float*)d_out;

  unsigned short* ws = (unsigned short*)d_ws;
  const long NE = 8L * 1024 * 1024;          // 8192*1024 elems
  unsigned short* Xqb = ws + 0 * NE;
  unsigned short* Xkb = ws + 1 * NE;
  unsigned short* Xvb = ws + 2 * NE;
  unsigned short* Qb  = ws + 3 * NE;
  unsigned short* Kb  = ws + 4 * NE;
  unsigned short* VTb = ws + 5 * NE;
  unsigned short* WQT = ws + 6 * NE;
  unsigned short* WKT = WQT + 1024 * 1024;
  unsigned short* WVT = WKT + 1024 * 1024;
  unsigned short* Sc  = ws;                  // 2^24 elems, aliases dead Xq+Xk

  dim3 b256(256);
  // 1. inputs -> bf16
  cvt_bf16<<<4096, b256, 0, stream>>>(Xq, Xqb, NE);
  cvt_bf16<<<4096, b256, 0, stream>>>(Xk, Xkb, NE);
  cvt_bf16<<<4096, b256, 0, stream>>>(Xv, Xvb, NE);
  // 2. weights -> bf16 transposed; fold 1/sqrt(1024) into WQT
  dim3 tg(32, 32), tb(32, 8);
  wtrans<<<tg, tb, 0, stream>>>(WQ, WQT, 0.03125f);
  wtrans<<<tg, tb, 0, stream>>>(WK, WKT, 1.0f);
  wtrans<<<tg, tb, 0, stream>>>(WV, WVT, 1.0f);
  // 3. projections: Q, K  [8192,1024]; VT [1024,8192]
  gemm_bt<unsigned short, false, false><<<dim3(8, 64, 1), b256, 0, stream>>>(
      Xqb, WQT, Qb, 8192, 1024, 1024, 1024, 1024, 1024, 0, 0, 0);
  gemm_bt<unsigned short, false, false><<<dim3(8, 64, 1), b256, 0, stream>>>(
      Xkb, WKT, Kb, 8192, 1024, 1024, 1024, 1024, 1024, 0, 0, 0);
  gemm_bt<unsigned short, false, false><<<dim3(64, 8, 1), b256, 0, stream>>>(
      WVT, Xvb, VTb, 1024, 8192, 1024, 1024, 1024, 8192, 0, 0, 0);
  // 4. scores: S_b = Q_b K_b^T (scale already in Q), skip above-diagonal tiles
  gemm_bt<unsigned short, true, false><<<dim3(16, 16, 4), b256, 0, stream>>>(
      Qb, Kb, Sc, 2048, 2048, 1024, 1024, 1024, 2048,
      2048L * 1024, 2048L * 1024, 2048L * 2048);
  // 5. causal softmax in place
  softmax_causal<<<8192, b256, 0, stream>>>(Sc);
  // 6. out_b = P_b V_b, K-loop clamped per row-block
  gemm_bt<float, false, true><<<dim3(8, 16, 4), b256, 0, stream>>>(
      Sc, VTb, out, 2048, 1024, 2048, 2048, 8192, 1024,
      2048L * 2048, 2048L, 2048L * 1024);
}

// Round 2
// 211.502 us; speedup vs baseline: 1.2271x; 1.2271x over previous
//
#include <hip/hip_runtime.h>
#include <stdint.h>

// ---------------------------------------------------------------------------
// AttentionHead: out = softmax_causal((Xq WQ)(Xk WK)^T / sqrt(D)) (Xv WV)
// B=4, S=2048, D=1024.  bf16 MFMA, f32 accumulate.
// Round 2: fused QKV projection dispatch (6 blocks/CU), double-buffered LDS
// with counted vmcnt (T3/T4 2-phase), vectorized register-resident softmax.
// ---------------------------------------------------------------------------

typedef __attribute__((ext_vector_type(8))) short short8;
typedef __attribute__((ext_vector_type(8))) unsigned short ushort8;
typedef __attribute__((ext_vector_type(4))) float f32x4;

__device__ __forceinline__ unsigned short f2bf(float f) {
  union { float f; unsigned u; } v; v.f = f;
  unsigned u = v.u + 0x7FFFu + ((v.u >> 16) & 1u);   // RNE
  return (unsigned short)(u >> 16);
}
__device__ __forceinline__ float bf2f(unsigned short h) {
  union { unsigned u; float f; } v; v.u = ((unsigned)h) << 16;
  return v.f;
}

__device__ __forceinline__ void gload16(const void* g, void* l) {
  __builtin_amdgcn_global_load_lds(
      (const __attribute__((address_space(1))) unsigned int*)g,
      (__attribute__((address_space(3))) unsigned int*)l, 16, 0, 0);
}

// ---------------- f32 -> bf16 convert, 3 tensors fused ----------------------
__global__ __launch_bounds__(256)
void cvt3_bf16(const float* __restrict__ Xq, const float* __restrict__ Xk,
               const float* __restrict__ Xv,
               unsigned short* __restrict__ Oq, unsigned short* __restrict__ Ok,
               unsigned short* __restrict__ Ov) {
  const int bx = blockIdx.x;
  const int op = bx >> 12, r = bx & 4095;          // 4096 blocks per tensor
  const float* in = op == 0 ? Xq : op == 1 ? Xk : Xv;
  unsigned short* out = op == 0 ? Oq : op == 1 ? Ok : Ov;
  const long i = ((long)r * 256 + threadIdx.x) * 8;
  float4 a = *(const float4*)(in + i);
  float4 b = *(const float4*)(in + i + 4);
  ushort8 rr;
  rr[0] = f2bf(a.x); rr[1] = f2bf(a.y); rr[2] = f2bf(a.z); rr[3] = f2bf(a.w);
  rr[4] = f2bf(b.x); rr[5] = f2bf(b.y); rr[6] = f2bf(b.z); rr[7] = f2bf(b.w);
  *(ushort8*)(out + i) = rr;
}

// ---------------- weight transpose x3: WT[e][k] = W[k][e]*scale -------------
__global__ __launch_bounds__(256)
void wtrans3(const float* __restrict__ WQ, const float* __restrict__ WK,
             const float* __restrict__ WV,
             unsigned short* __restrict__ WQT, unsigned short* __restrict__ WKT,
             unsigned short* __restrict__ WVT) {
  const int z = blockIdx.z;
  const float* W = z == 0 ? WQ : z == 1 ? WK : WV;
  unsigned short* WT = z == 0 ? WQT : z == 1 ? WKT : WVT;
  const float scale = z == 0 ? 0.03125f : 1.0f;    // 1/sqrt(1024) into WQT
  __shared__ float t[32][33];
  const int bk = blockIdx.x * 32, be = blockIdx.y * 32;
  const int tx = threadIdx.x, ty = threadIdx.y;    // (32,8)
#pragma unroll
  for (int j = 0; j < 32; j += 8)
    t[ty + j][tx] = W[(long)(bk + ty + j) * 1024 + (be + tx)];
  __syncthreads();
#pragma unroll
  for (int j = 0; j < 32; j += 8)
    WT[(long)(be + ty + j) * 1024 + (bk + tx)] = f2bf(t[tx][ty + j] * scale);
}

// ---------------- B^T-layout bf16 GEMM, dbuf + counted vmcnt ----------------
// C[m][n] = sum_k A[m][k] * B[n][k];  one 128x128 tile at (bm,bn).
template<typename CT, bool KCLAMP>
__device__ __forceinline__ void gemm_body(const unsigned short* __restrict__ A,
                                          const unsigned short* __restrict__ B,
                                          CT* __restrict__ C,
                                          int bm, int bn, int K,
                                          int lda, int ldb, int ldc) {
  __shared__ __align__(16) unsigned short Al[2][128 * 32];
  __shared__ __align__(16) unsigned short Bl[2][128 * 32];

  const int tid = threadIdx.x;
  const int lane = tid & 63;
  const int wid = tid >> 6;
  const int wr = wid >> 1, wc = wid & 1;        // wave owns 64x64 at (wr,wc)
  const int fr = lane & 15;                     // frag row/col within 16
  const int fq = lane >> 4;                     // k-chunk of 8
  const int m0 = bm * 128, n0 = bn * 128;
  const int kmax = KCLAMP ? min(K, (bm + 1) * 128) : K;
  const int nt = kmax >> 5;

  f32x4 acc[4][4] = {};

  const int soff = tid * 8;                     // linear LDS dest (lane*16B)
  const unsigned short* Aps = A + (long)(m0 + (tid >> 2)) * lda + ((tid & 3) << 3);
  const unsigned short* Bps = B + (long)(n0 + (tid >> 2)) * ldb + ((tid & 3) << 3);
  const long a64 = 64L * lda, b64 = 64L * ldb;

#define STAGE(bf, k0)                                   \
  do {                                                  \
    gload16(Aps + (k0),       &Al[bf][soff]);           \
    gload16(Aps + a64 + (k0), &Al[bf][64 * 32 + soff]); \
    gload16(Bps + (k0),       &Bl[bf][soff]);           \
    gload16(Bps + b64 + (k0), &Bl[bf][64 * 32 + soff]); \
  } while (0)

  STAGE(0, 0);
  for (int t = 0; t < nt; ++t) {
    const int cur = t & 1;
    if (t + 1 < nt) {
      STAGE(cur ^ 1, (t + 1) << 5);                    // next tile in flight
      asm volatile("s_waitcnt vmcnt(4)" ::: "memory"); // current tile landed
    } else {
      asm volatile("s_waitcnt vmcnt(0)" ::: "memory");
    }
    asm volatile("s_barrier" ::: "memory");            // all waves: buf ready
    short8 af[4], bfr[4];
#pragma unroll
    for (int m = 0; m < 4; ++m)
      af[m] = *(const short8*)&Al[cur][(wr * 64 + m * 16 + fr) * 32 + fq * 8];
#pragma unroll
    for (int n = 0; n < 4; ++n)
      bfr[n] = *(const short8*)&Bl[cur][(wc * 64 + n * 16 + fr) * 32 + fq * 8];
#pragma unroll
    for (int m = 0; m < 4; ++m)
#pragma unroll
      for (int n = 0; n < 4; ++n)
        acc[m][n] = __builtin_amdgcn_mfma_f32_16x16x32_bf16(af[m], bfr[n], acc[m][n], 0, 0, 0);
    asm volatile("s_barrier" ::: "memory");            // reads done before overwrite
  }
#undef STAGE

  // C/D layout (verified m89/m91): col = lane&15, row = (lane>>4)*4 + reg
#pragma unroll
  for (int m = 0; m < 4; ++m) {
    const int row = m0 + wr * 64 + m * 16 + fq * 4;
#pragma unroll
    for (int n = 0; n < 4; ++n) {
      const int col = n0 + wc * 64 + n * 16 + fr;
#pragma unroll
      for (int r = 0; r < 4; ++r) {
        float v = acc[m][n][r];
        if constexpr (sizeof(CT) == 2)
          C[(long)(row + r) * ldc + col] = (CT)f2bf(v);
        else
          C[(long)(row + r) * ldc + col] = (CT)v;
      }
    }
  }
}

// Fused Q/K/VT projections: 1536 blocks -> 6 blocks/CU.
__global__ __launch_bounds__(256)
void qkv_gemm(const unsigned short* __restrict__ Xq, const unsigned short* __restrict__ WQT,
              unsigned short* __restrict__ Q,
              const unsigned short* __restrict__ Xk, const unsigned short* __restrict__ WKT,
              unsigned short* __restrict__ Kk,
              const unsigned short* __restrict__ WVT, const unsigned short* __restrict__ Xv,
              unsigned short* __restrict__ VT) {
  const int bx = blockIdx.x;
  const unsigned short *A, *B;
  unsigned short* C;
  int bm, bn, ldc = 1024;
  if (bx < 512)       { A = Xq;  B = WQT; C = Q;  bm = bx >> 3;  bn = bx & 7; }
  else if (bx < 1024) { int r = bx - 512;  A = Xk;  B = WKT; C = Kk; bm = r >> 3; bn = r & 7; }
  else                { int r = bx - 1024; A = WVT; B = Xv;  C = VT; bm = r >> 6; bn = r & 63; ldc = 8192; }
  gemm_body<unsigned short, false>(A, B, C, bm, bn, 1024, 1024, 1024, ldc);
}

// Scores: S_b = Q_b K_b^T (scale folded into Q); skip above-diagonal tiles.
__global__ __launch_bounds__(256)
void scores_gemm(const unsigned short* __restrict__ Q, const unsigned short* __restrict__ K,
                 unsigned short* __restrict__ S) {
  const int bn = blockIdx.x, bm = blockIdx.y, bz = blockIdx.z;
  if (bn > bm) return;
  gemm_body<unsigned short, false>(Q + (long)bz * 2048 * 1024, K + (long)bz * 2048 * 1024,
                                   S + (long)bz * 2048 * 2048, bm, bn, 1024, 1024, 1024, 2048);
}

// PV: out_b = P_b V_b; K-loop clamped at the causal boundary per row-block.
__global__ __launch_bounds__(256)
void pv_gemm(const unsigned short* __restrict__ P, const unsigned short* __restrict__ VT,
             float* __restrict__ O) {
  const int bn = blockIdx.x, bm = blockIdx.y, bz = blockIdx.z;
  gemm_body<float, true>(P + (long)bz * 2048 * 2048, VT + (long)bz * 2048,
                         O + (long)bz * 2048 * 1024, bm, bn, 2048, 2048, 8192, 1024);
}

// ---------------- causal softmax, vectorized, register-resident -------------
__global__ __launch_bounds__(256)
void softmax_causal(unsigned short* __restrict__ P) {
  const int row = blockIdx.x;              // b*2048 + q
  const int q = row & 2047;
  unsigned short* p = P + (long)row * 2048;
  const int nfill = ((q >> 7) + 1) << 7;   // PV reads up to this 128-boundary
  const int tid = threadIdx.x;
  const int lane = tid & 63, wid = tid >> 6;
  const int i0 = tid * 8;
  __shared__ float red[8];

  ushort8 v8 = *(const ushort8*)(p + i0);  // full row; mask below
  float v[8];
  float lmax = -3.0e38f;
#pragma unroll
  for (int j = 0; j < 8; ++j) {
    float f = bf2f(v8[j]);
    f = (i0 + j <= q) ? f : -3.0e38f;
    v[j] = f;
    lmax = fmaxf(lmax, f);
  }
#pragma unroll
  for (int off = 1; off < 64; off <<= 1)
    lmax = fmaxf(lmax, __shfl_xor(lmax, off));
  if (lane == 0) red[wid] = lmax;
  __syncthreads();
  const float mx = fmaxf(fmaxf(red[0], red[1]), fmaxf(red[2], red[3]));

  float lsum = 0.f;
#pragma unroll
  for (int j = 0; j < 8; ++j) {
    float e = __expf(v[j] - mx);           // masked lanes -> exp(-huge) = 0
    v[j] = e;
    lsum += e;
  }
#pragma unroll
  for (int off = 1; off < 64; off <<= 1)
    lsum += __shfl_xor(lsum, off);
  if (lane == 0) red[4 + wid] = lsum;
  __syncthreads();
  const float inv = 1.0f / (red[4] + red[5] + red[6] + red[7]);

  if (i0 < nfill) {
    ushort8 r;
#pragma unroll
    for (int j = 0; j < 8; ++j)
      r[j] = (i0 + j <= q) ? f2bf(v[j] * inv) : (unsigned short)0;
    *(ushort8*)(p + i0) = r;
  }
}

// ---------------------------------------------------------------------------
extern "C" void kernel_launch(void* const* d_in, const int* in_sizes, int n_in,
                              void* d_out, int out_size, void* d_ws, size_t ws_size,
                              hipStream_t stream) {
  const float* Xk = (const float*)d_in[0];
  const float* Xv = (const float*)d_in[1];
  const float* Xq = (const float*)d_in[2];
  const float* WK = (const float*)d_in[3];
  const float* WQ = (const float*)d_in[4];
  const float* WV = (const float*)d_in[5];
  float* out = (float*)d_out;

  unsigned short* ws = (unsigned short*)d_ws;
  const long NE = 8L * 1024 * 1024;          // 8192*1024 elems
  unsigned short* Xqb = ws + 0 * NE;
  unsigned short* Xkb = ws + 1 * NE;
  unsigned short* Xvb = ws + 2 * NE;
  unsigned short* Qb  = ws + 3 * NE;
  unsigned short* Kb  = ws + 4 * NE;
  unsigned short* VTb = ws + 5 * NE;
  unsigned short* WQT = ws + 6 * NE;
  unsigned short* WKT = WQT + 1024 * 1024;
  unsigned short* WVT = WKT + 1024 * 1024;
  unsigned short* Sc  = ws;                  // 2^24 elems, aliases dead Xq+Xk

  dim3 b256(256);
  cvt3_bf16<<<12288, b256, 0, stream>>>(Xq, Xk, Xv, Xqb, Xkb, Xvb);
  wtrans3<<<dim3(32, 32, 3), dim3(32, 8), 0, stream>>>(WQ, WK, WV, WQT, WKT, WVT);
  qkv_gemm<<<1536, b256, 0, stream>>>(Xqb, WQT, Qb, Xkb, WKT, Kb, WVT, Xvb, VTb);
  scores_gemm<<<dim3(16, 16, 4), b256, 0, stream>>>(Qb, Kb, Sc);
  softmax_causal<<<8192, b256, 0, stream>>>(Sc);
  pv_gemm<<<dim3(8, 16, 4), b256, 0, stream>>>(Sc, VTb, out);
}

// Round 3
// 190.122 us; speedup vs baseline: 1.3651x; 1.1125x over previous
//
#include <hip/hip_runtime.h>
#include <stdint.h>

// ---------------------------------------------------------------------------
// AttentionHead: out = softmax_causal((Xq WQ)(Xk WK)^T / sqrt(D)) (Xv WV)
// B=4, S=2048, D=1024.  bf16 MFMA, f32 accumulate.
// Round 3: 256-wide tiles with the 8-phase-style schedule in plain HIP:
//   - k-half-granular staging (lane-linear LDS dest for global_load_lds)
//   - counted vmcnt ledger (never drains mid-loop), 3 barriers/K-tile
//   - XOR bank swizzle: pre-swizzled global source + swizzled ds_read
//   - s_setprio around MFMA clusters, XCD-aware block swizzle
// ---------------------------------------------------------------------------

typedef __attribute__((ext_vector_type(8))) short short8;
typedef __attribute__((ext_vector_type(8))) unsigned short ushort8;
typedef __attribute__((ext_vector_type(4))) float f32x4;

__device__ __forceinline__ unsigned short f2bf(float f) {
  union { float f; unsigned u; } v; v.f = f;
  unsigned u = v.u + 0x7FFFu + ((v.u >> 16) & 1u);   // RNE
  return (unsigned short)(u >> 16);
}
__device__ __forceinline__ float bf2f(unsigned short h) {
  union { unsigned u; float f; } v; v.u = ((unsigned)h) << 16;
  return v.f;
}

__device__ __forceinline__ void gload16(const void* g, void* l) {
  __builtin_amdgcn_global_load_lds(
      (const __attribute__((address_space(1))) unsigned int*)g,
      (__attribute__((address_space(3))) unsigned int*)l, 16, 0, 0);
}

template<int N> __device__ __forceinline__ void vmwait() {
  static_assert(N >= 0 && N <= 8, "vmcnt range");
  if constexpr (N == 0) asm volatile("s_waitcnt vmcnt(0)" ::: "memory");
  else if constexpr (N == 1) asm volatile("s_waitcnt vmcnt(1)" ::: "memory");
  else if constexpr (N == 2) asm volatile("s_waitcnt vmcnt(2)" ::: "memory");
  else if constexpr (N == 3) asm volatile("s_waitcnt vmcnt(3)" ::: "memory");
  else if constexpr (N == 4) asm volatile("s_waitcnt vmcnt(4)" ::: "memory");
  else if constexpr (N == 5) asm volatile("s_waitcnt vmcnt(5)" ::: "memory");
  else if constexpr (N == 6) asm volatile("s_waitcnt vmcnt(6)" ::: "memory");
  else if constexpr (N == 7) asm volatile("s_waitcnt vmcnt(7)" ::: "memory");
  else asm volatile("s_waitcnt vmcnt(8)" ::: "memory");
}
__device__ __forceinline__ void barrier_() { asm volatile("s_barrier" ::: "memory"); }
__device__ __forceinline__ void lgkm0() { asm volatile("s_waitcnt lgkmcnt(0)" ::: "memory"); }

// ---------------- f32 -> bf16 convert, 3 tensors fused ----------------------
__global__ __launch_bounds__(256)
void cvt3_bf16(const float* __restrict__ Xq, const float* __restrict__ Xk,
               const float* __restrict__ Xv,
               unsigned short* __restrict__ Oq, unsigned short* __restrict__ Ok,
               unsigned short* __restrict__ Ov) {
  const int bx = blockIdx.x;
  const int op = bx >> 12, r = bx & 4095;          // 4096 blocks per tensor
  const float* in = op == 0 ? Xq : op == 1 ? Xk : Xv;
  unsigned short* out = op == 0 ? Oq : op == 1 ? Ok : Ov;
  const long i = ((long)r * 256 + threadIdx.x) * 8;
  float4 a = *(const float4*)(in + i);
  float4 b = *(const float4*)(in + i + 4);
  ushort8 rr;
  rr[0] = f2bf(a.x); rr[1] = f2bf(a.y); rr[2] = f2bf(a.z); rr[3] = f2bf(a.w);
  rr[4] = f2bf(b.x); rr[5] = f2bf(b.y); rr[6] = f2bf(b.z); rr[7] = f2bf(b.w);
  *(ushort8*)(out + i) = rr;
}

// ---------------- weight transpose x3: WT[e][k] = W[k][e]*scale -------------
__global__ __launch_bounds__(256)
void wtrans3(const float* __restrict__ WQ, const float* __restrict__ WK,
             const float* __restrict__ WV,
             unsigned short* __restrict__ WQT, unsigned short* __restrict__ WKT,
             unsigned short* __restrict__ WVT) {
  const int z = blockIdx.z;
  const float* W = z == 0 ? WQ : z == 1 ? WK : WV;
  unsigned short* WT = z == 0 ? WQT : z == 1 ? WKT : WVT;
  const float scale = z == 0 ? 0.03125f : 1.0f;    // 1/sqrt(1024) into WQT
  __shared__ float t[32][33];
  const int bk = blockIdx.x * 32, be = blockIdx.y * 32;
  const int tx = threadIdx.x, ty = threadIdx.y;    // (32,8)
#pragma unroll
  for (int j = 0; j < 32; j += 8)
    t[ty + j][tx] = W[(long)(bk + ty + j) * 1024 + (be + tx)];
  __syncthreads();
#pragma unroll
  for (int j = 0; j < 32; j += 8)
    WT[(long)(be + ty + j) * 1024 + (bk + tx)] = f2bf(t[tx][ty + j] * scale);
}

// ---------------- B^T-layout bf16 GEMM, 256-class tile, counted vmcnt -------
// C[m][n] = sum_k A[m][k]*B[n][k].  BM=MF*32, BN=NF*64.  8 waves (2Mx4N).
// LDS: [buf][khalf][rows][32 cols], swizzled slot = fq ^ (row&3).
template<typename CT, int MF, int NF>
__device__ __forceinline__ void gemm_body(const unsigned short* __restrict__ A,
                                          const unsigned short* __restrict__ B,
                                          CT* __restrict__ C,
                                          int bm, int bn, int kmax,
                                          int lda, int ldb, int ldc) {
  constexpr int BM = MF * 32, BN = NF * 64;
  constexpr int LA = BM / 128, LB = BN / 128;      // gloads per half-stage
  constexpr int V = 2 * LA + LB;                   // steady-state vmcnt
  __shared__ __align__(16) unsigned short Al[2 * 2 * BM * 32];
  __shared__ __align__(16) unsigned short Bl[2 * 2 * BN * 32];

  const int tid = threadIdx.x;                     // 0..511
  const int lane = tid & 63, wid = tid >> 6;
  const int wr = wid >> 2, wc = wid & 3;           // 2x4 wave grid
  const int fr = lane & 15, fq = lane >> 4;
  const int srow = tid >> 2;                       // staging row 0..127
  const int scol = (((tid & 3) ^ ((tid >> 2) & 3)) << 3);  // pre-swizzled src col
  const int m0 = bm * BM, n0 = bn * BN;
  const int nt = kmax >> 6;

  f32x4 acc[MF][NF] = {};

  const unsigned short* As = A + (long)(m0 + srow) * lda + scol;
  const unsigned short* Bs = B + (long)(n0 + srow) * ldb + scol;
  char* AL = (char*)Al;
  char* BL = (char*)Bl;

  auto stageA = [&](int b, int h, int kt) {        // A k-half h of tile kt
#pragma unroll
    for (int l = 0; l < LA; ++l)
      gload16(As + (long)l * 128 * lda + kt * 64 + h * 32,
              AL + b * (BM * 128) + h * (BM * 64) + l * 8192 + tid * 16);
  };
  auto stageB = [&](int b, int h, int kt) {
#pragma unroll
    for (int l = 0; l < LB; ++l)
      gload16(Bs + (long)l * 128 * ldb + kt * 64 + h * 32,
              BL + b * (BN * 128) + h * (BN * 64) + l * 8192 + tid * 16);
  };

  const int aoff = (wr * (BM / 2) + fr) * 64 + ((fq ^ (fr & 3)) << 4);
  const int boff = (wc * (BN / 4) + fr) * 64 + ((fq ^ (fr & 3)) << 4);
  auto ardf = [&](int b, int kk, int m) -> short8 {
    return *(const short8*)(AL + b * (BM * 128) + kk * (BM * 64) + aoff + m * 1024);
  };
  auto brdf = [&](int b, int kk, int n) -> short8 {
    return *(const short8*)(BL + b * (BN * 128) + kk * (BN * 64) + boff + n * 1024);
  };

  // prologue: tile 0 -> buf 0   (order: A-k0, B-k0, A-k1, B-k1)
  stageA(0, 0, 0); stageB(0, 0, 0); stageA(0, 1, 0); stageB(0, 1, 0);

  for (int u = 0; u < nt; ++u) {
    const int cb = u & 1, nb = cb ^ 1;
    const bool pf = (u + 1 < nt);
    lgkm0();                                   // my ds_reads of buf nb serviced
    barrier_();                                // all waves done reading buf nb
    if (pf) { stageA(nb, 0, u + 1); vmwait<V>(); }   // retire tile-u k0 halves
    else    { vmwait<LA + LB>(); }
    barrier_();                                // k-half 0 resident for all
    short8 bfr[NF], af[MF / 2];
#pragma unroll
    for (int n = 0; n < NF; ++n) bfr[n] = brdf(cb, 0, n);
#pragma unroll
    for (int m = 0; m < MF / 2; ++m) af[m] = ardf(cb, 0, m);
    if (pf) stageB(nb, 0, u + 1);
    __builtin_amdgcn_s_setprio(1);
#pragma unroll
    for (int m = 0; m < MF / 2; ++m)
#pragma unroll
      for (int n = 0; n < NF; ++n)
        acc[m][n] = __builtin_amdgcn_mfma_f32_16x16x32_bf16(af[m], bfr[n], acc[m][n], 0, 0, 0);
    __builtin_amdgcn_s_setprio(0);
#pragma unroll
    for (int m = 0; m < MF / 2; ++m) af[m] = ardf(cb, 0, MF / 2 + m);
    if (pf) stageA(nb, 1, u + 1);
    __builtin_amdgcn_s_setprio(1);
#pragma unroll
    for (int m = 0; m < MF / 2; ++m)
#pragma unroll
      for (int n = 0; n < NF; ++n)
        acc[MF / 2 + m][n] =
            __builtin_amdgcn_mfma_f32_16x16x32_bf16(af[m], bfr[n], acc[MF / 2 + m][n], 0, 0, 0);
    __builtin_amdgcn_s_setprio(0);
    if (pf) vmwait<V>(); else vmwait<0>();     // retire tile-u k1 halves
    barrier_();                                // k-half 1 resident for all
#pragma unroll
    for (int n = 0; n < NF; ++n) bfr[n] = brdf(cb, 1, n);
#pragma unroll
    for (int m = 0; m < MF / 2; ++m) af[m] = ardf(cb, 1, m);
    if (pf) stageB(nb, 1, u + 1);
    __builtin_amdgcn_s_setprio(1);
#pragma unroll
    for (int m = 0; m < MF / 2; ++m)
#pragma unroll
      for (int n = 0; n < NF; ++n)
        acc[m][n] = __builtin_amdgcn_mfma_f32_16x16x32_bf16(af[m], bfr[n], acc[m][n], 0, 0, 0);
    __builtin_amdgcn_s_setprio(0);
#pragma unroll
    for (int m = 0; m < MF / 2; ++m) af[m] = ardf(cb, 1, MF / 2 + m);
    __builtin_amdgcn_s_setprio(1);
#pragma unroll
    for (int m = 0; m < MF / 2; ++m)
#pragma unroll
      for (int n = 0; n < NF; ++n)
        acc[MF / 2 + m][n] =
            __builtin_amdgcn_mfma_f32_16x16x32_bf16(af[m], bfr[n], acc[MF / 2 + m][n], 0, 0, 0);
    __builtin_amdgcn_s_setprio(0);
  }

  // C/D layout: col = lane&15, row = (lane>>4)*4 + reg
#pragma unroll
  for (int m = 0; m < MF; ++m) {
    const int row = m0 + wr * (BM / 2) + m * 16 + fq * 4;
#pragma unroll
    for (int n = 0; n < NF; ++n) {
      const int col = n0 + wc * (BN / 4) + n * 16 + fr;
#pragma unroll
      for (int r = 0; r < 4; ++r) {
        float v = acc[m][n][r];
        if constexpr (sizeof(CT) == 2)
          C[(long)(row + r) * ldc + col] = (CT)f2bf(v);
        else
          C[(long)(row + r) * ldc + col] = (CT)v;
      }
    }
  }
}

// Fused Q/K/VT projections: 384 blocks, XCD-swizzled.
__global__ __launch_bounds__(512, 2)
void qkv_gemm(const unsigned short* __restrict__ Xq, const unsigned short* __restrict__ WQT,
              unsigned short* __restrict__ Q,
              const unsigned short* __restrict__ Xk, const unsigned short* __restrict__ WKT,
              unsigned short* __restrict__ Kk,
              const unsigned short* __restrict__ WVT, const unsigned short* __restrict__ Xv,
              unsigned short* __restrict__ VT) {
  const int id = (blockIdx.x & 7) * 48 + (blockIdx.x >> 3);   // 384 % 8 == 0
  const unsigned short *A, *B;
  unsigned short* C;
  int bm, bn, ldc = 1024;
  if (id < 128)      { A = Xq;  B = WQT; C = Q;  bm = id >> 2;        bn = id & 3; }
  else if (id < 256) { int r = id - 128; A = Xk;  B = WKT; C = Kk; bm = r >> 2;  bn = r & 3; }
  else               { int r = id - 256; A = WVT; B = Xv;  C = VT; bm = r >> 5;  bn = r & 31; ldc = 8192; }
  gemm_body<unsigned short, 8, 4>(A, B, C, bm, bn, 1024, 1024, 1024, ldc);
}

// Scores: S_b = Q_b K_b^T (scale in Q); skip above-diagonal 256-tiles.
__global__ __launch_bounds__(512, 2)
void scores_gemm(const unsigned short* __restrict__ Q, const unsigned short* __restrict__ K,
                 unsigned short* __restrict__ S) {
  const int id = (blockIdx.x & 7) * 32 + (blockIdx.x >> 3);   // 256 % 8 == 0
  const int bz = id >> 6, r = id & 63, bm = r >> 3, bn = r & 7;
  if (bn > bm) return;
  gemm_body<unsigned short, 8, 4>(Q + (long)bz * 2048 * 1024, K + (long)bz * 2048 * 1024,
                                  S + (long)bz * 2048 * 2048, bm, bn, 1024, 1024, 1024, 2048);
}

// PV: out_b = P_b V_b; 128x256 tiles, K clamped at causal boundary.
__global__ __launch_bounds__(512, 2)
void pv_gemm(const unsigned short* __restrict__ P, const unsigned short* __restrict__ VT,
             float* __restrict__ O) {
  const int id = (blockIdx.x & 7) * 32 + (blockIdx.x >> 3);   // 256 % 8 == 0
  const int bz = id >> 6, r = id & 63, bm = r >> 2, bn = r & 3;  // bm 0..15
  gemm_body<float, 4, 4>(P + (long)bz * 2048 * 2048, VT + (long)bz * 2048,
                         O + (long)bz * 2048 * 1024, bm, bn, (bm + 1) * 128,
                         2048, 8192, 1024);
}

// ---------------- causal softmax, vectorized, register-resident -------------
__global__ __launch_bounds__(256)
void softmax_causal(unsigned short* __restrict__ P) {
  const int row = blockIdx.x;              // b*2048 + q
  const int q = row & 2047;
  unsigned short* p = P + (long)row * 2048;
  const int nfill = ((q >> 7) + 1) << 7;   // PV reads up to this 128-boundary
  const int tid = threadIdx.x;
  const int lane = tid & 63, wid = tid >> 6;
  const int i0 = tid * 8;
  __shared__ float red[8];

  ushort8 v8 = *(const ushort8*)(p + i0);  // full row; mask below
  float v[8];
  float lmax = -3.0e38f;
#pragma unroll
  for (int j = 0; j < 8; ++j) {
    float f = bf2f(v8[j]);
    f = (i0 + j <= q) ? f : -3.0e38f;
    v[j] = f;
    lmax = fmaxf(lmax, f);
  }
#pragma unroll
  for (int off = 1; off < 64; off <<= 1)
    lmax = fmaxf(lmax, __shfl_xor(lmax, off));
  if (lane == 0) red[wid] = lmax;
  __syncthreads();
  const float mx = fmaxf(fmaxf(red[0], red[1]), fmaxf(red[2], red[3]));

  float lsum = 0.f;
#pragma unroll
  for (int j = 0; j < 8; ++j) {
    float e = __expf(v[j] - mx);           // masked lanes -> exp(-huge) = 0
    v[j] = e;
    lsum += e;
  }
#pragma unroll
  for (int off = 1; off < 64; off <<= 1)
    lsum += __shfl_xor(lsum, off);
  if (lane == 0) red[4 + wid] = lsum;
  __syncthreads();
  const float inv = 1.0f / (red[4] + red[5] + red[6] + red[7]);

  if (i0 < nfill) {
    ushort8 r;
#pragma unroll
    for (int j = 0; j < 8; ++j)
      r[j] = (i0 + j <= q) ? f2bf(v[j] * inv) : (unsigned short)0;
    *(ushort8*)(p + i0) = r;
  }
}

// ---------------------------------------------------------------------------
extern "C" void kernel_launch(void* const* d_in, const int* in_sizes, int n_in,
                              void* d_out, int out_size, void* d_ws, size_t ws_size,
                              hipStream_t stream) {
  const float* Xk = (const float*)d_in[0];
  const float* Xv = (const float*)d_in[1];
  const float* Xq = (const float*)d_in[2];
  const float* WK = (const float*)d_in[3];
  const float* WQ = (const float*)d_in[4];
  const float* WV = (const float*)d_in[5];
  float* out = (float*)d_out;

  unsigned short* ws = (unsigned short*)d_ws;
  const long NE = 8L * 1024 * 1024;          // 8192*1024 elems
  unsigned short* Xqb = ws + 0 * NE;
  unsigned short* Xkb = ws + 1 * NE;
  unsigned short* Xvb = ws + 2 * NE;
  unsigned short* Qb  = ws + 3 * NE;
  unsigned short* Kb  = ws + 4 * NE;
  unsigned short* VTb = ws + 5 * NE;
  unsigned short* WQT = ws + 6 * NE;
  unsigned short* WKT = WQT + 1024 * 1024;
  unsigned short* WVT = WKT + 1024 * 1024;
  unsigned short* Sc  = ws;                  // 2^24 elems, aliases dead Xq+Xk

  dim3 b256(256), b512(512);
  cvt3_bf16<<<12288, b256, 0, stream>>>(Xq, Xk, Xv, Xqb, Xkb, Xvb);
  wtrans3<<<dim3(32, 32, 3), dim3(32, 8), 0, stream>>>(WQ, WK, WV, WQT, WKT, WVT);
  qkv_gemm<<<384, b512, 0, stream>>>(Xqb, WQT, Qb, Xkb, WKT, Kb, WVT, Xvb, VTb);
  scores_gemm<<<256, b512, 0, stream>>>(Qb, Kb, Sc);
  softmax_causal<<<8192, b256, 0, stream>>>(Sc);
  pv_gemm<<<256, b512, 0, stream>>>(Sc, VTb, out);
}

// Round 4
// 177.177 us; speedup vs baseline: 1.4648x; 1.0731x over previous
//
#include <hip/hip_runtime.h>
#include <stdint.h>

// ---------------------------------------------------------------------------
// AttentionHead: out = softmax_causal((Xq WQ)(Xk WK)^T / sqrt(D)) (Xv WV)
// B=4, S=2048, D=1024.  bf16 MFMA, f32 accumulate.
// Round 4: fixed LDS bank swizzle (key (row>>1)&3 for 64B rows — old key
// left 4-way conflicts), pv re-tiled to 128x128 with heavy+light pairing
// (2 blocks/CU, every CU gets K-sum 2176).
// ---------------------------------------------------------------------------

typedef __attribute__((ext_vector_type(8))) short short8;
typedef __attribute__((ext_vector_type(8))) unsigned short ushort8;
typedef __attribute__((ext_vector_type(4))) float f32x4;

__device__ __forceinline__ unsigned short f2bf(float f) {
  union { float f; unsigned u; } v; v.f = f;
  unsigned u = v.u + 0x7FFFu + ((v.u >> 16) & 1u);   // RNE
  return (unsigned short)(u >> 16);
}
__device__ __forceinline__ float bf2f(unsigned short h) {
  union { unsigned u; float f; } v; v.u = ((unsigned)h) << 16;
  return v.f;
}

__device__ __forceinline__ void gload16(const void* g, void* l) {
  __builtin_amdgcn_global_load_lds(
      (const __attribute__((address_space(1))) unsigned int*)g,
      (__attribute__((address_space(3))) unsigned int*)l, 16, 0, 0);
}

template<int N> __device__ __forceinline__ void vmwait() {
  static_assert(N >= 0 && N <= 8, "vmcnt range");
  if constexpr (N == 0) asm volatile("s_waitcnt vmcnt(0)" ::: "memory");
  else if constexpr (N == 1) asm volatile("s_waitcnt vmcnt(1)" ::: "memory");
  else if constexpr (N == 2) asm volatile("s_waitcnt vmcnt(2)" ::: "memory");
  else if constexpr (N == 3) asm volatile("s_waitcnt vmcnt(3)" ::: "memory");
  else if constexpr (N == 4) asm volatile("s_waitcnt vmcnt(4)" ::: "memory");
  else if constexpr (N == 5) asm volatile("s_waitcnt vmcnt(5)" ::: "memory");
  else if constexpr (N == 6) asm volatile("s_waitcnt vmcnt(6)" ::: "memory");
  else if constexpr (N == 7) asm volatile("s_waitcnt vmcnt(7)" ::: "memory");
  else asm volatile("s_waitcnt vmcnt(8)" ::: "memory");
}
__device__ __forceinline__ void barrier_() { asm volatile("s_barrier" ::: "memory"); }
__device__ __forceinline__ void lgkm0() { asm volatile("s_waitcnt lgkmcnt(0)" ::: "memory"); }

// ---------------- f32 -> bf16 convert, 3 tensors fused ----------------------
__global__ __launch_bounds__(256)
void cvt3_bf16(const float* __restrict__ Xq, const float* __restrict__ Xk,
               const float* __restrict__ Xv,
               unsigned short* __restrict__ Oq, unsigned short* __restrict__ Ok,
               unsigned short* __restrict__ Ov) {
  const int bx = blockIdx.x;
  const int op = bx >> 12, r = bx & 4095;          // 4096 blocks per tensor
  const float* in = op == 0 ? Xq : op == 1 ? Xk : Xv;
  unsigned short* out = op == 0 ? Oq : op == 1 ? Ok : Ov;
  const long i = ((long)r * 256 + threadIdx.x) * 8;
  float4 a = *(const float4*)(in + i);
  float4 b = *(const float4*)(in + i + 4);
  ushort8 rr;
  rr[0] = f2bf(a.x); rr[1] = f2bf(a.y); rr[2] = f2bf(a.z); rr[3] = f2bf(a.w);
  rr[4] = f2bf(b.x); rr[5] = f2bf(b.y); rr[6] = f2bf(b.z); rr[7] = f2bf(b.w);
  *(ushort8*)(out + i) = rr;
}

// ---------------- weight transpose x3: WT[e][k] = W[k][e]*scale -------------
__global__ __launch_bounds__(256)
void wtrans3(const float* __restrict__ WQ, const float* __restrict__ WK,
             const float* __restrict__ WV,
             unsigned short* __restrict__ WQT, unsigned short* __restrict__ WKT,
             unsigned short* __restrict__ WVT) {
  const int z = blockIdx.z;
  const float* W = z == 0 ? WQ : z == 1 ? WK : WV;
  unsigned short* WT = z == 0 ? WQT : z == 1 ? WKT : WVT;
  const float scale = z == 0 ? 0.03125f : 1.0f;    // 1/sqrt(1024) into WQT
  __shared__ float t[32][33];
  const int bk = blockIdx.x * 32, be = blockIdx.y * 32;
  const int tx = threadIdx.x, ty = threadIdx.y;    // (32,8)
#pragma unroll
  for (int j = 0; j < 32; j += 8)
    t[ty + j][tx] = W[(long)(bk + ty + j) * 1024 + (be + tx)];
  __syncthreads();
#pragma unroll
  for (int j = 0; j < 32; j += 8)
    WT[(long)(be + ty + j) * 1024 + (bk + tx)] = f2bf(t[tx][ty + j] * scale);
}

// ---------------- B^T-layout bf16 GEMM, 8-phase, counted vmcnt --------------
// C[m][n] = sum_k A[m][k]*B[n][k].  BM=MF*32, BN=NF*64.  8 waves (2Mx4N).
// LDS: [buf][khalf][row][32 cols]; 16B slot swizzle: slot ^= (row>>1)&3
// (64B rows alias banks with period 2; this key makes only fr/fr+8 collide
//  = 2-way = free).  Source pre-swizzled to match (both-sides involution).
template<typename CT, int MF, int NF>
__device__ __forceinline__ void gemm_body(const unsigned short* __restrict__ A,
                                          const unsigned short* __restrict__ B,
                                          CT* __restrict__ C,
                                          int bm, int bn, int kmax,
                                          int lda, int ldb, int ldc) {
  constexpr int BM = MF * 32, BN = NF * 64;
  constexpr int LA = BM / 128, LB = BN / 128;      // gloads per half-stage
  constexpr int V = 2 * LA + LB;                   // steady-state vmcnt
  __shared__ __align__(16) unsigned short Al[2 * 2 * BM * 32];
  __shared__ __align__(16) unsigned short Bl[2 * 2 * BN * 32];

  const int tid = threadIdx.x;                     // 0..511
  const int lane = tid & 63, wid = tid >> 6;
  const int wr = wid >> 2, wc = wid & 3;           // 2x4 wave grid
  const int fr = lane & 15, fq = lane >> 4;
  const int srow = tid >> 2;                       // staging row 0..127
  const int scol = (((tid & 3) ^ ((tid >> 3) & 3)) << 3);  // pre-swz src col
  const int m0 = bm * BM, n0 = bn * BN;
  const int nt = kmax >> 6;

  f32x4 acc[MF][NF] = {};

  const unsigned short* As = A + (long)(m0 + srow) * lda + scol;
  const unsigned short* Bs = B + (long)(n0 + srow) * ldb + scol;
  char* AL = (char*)Al;
  char* BL = (char*)Bl;

  auto stageA = [&](int b, int h, int kt) {        // A k-half h of tile kt
#pragma unroll
    for (int l = 0; l < LA; ++l)
      gload16(As + (long)l * 128 * lda + kt * 64 + h * 32,
              AL + b * (BM * 128) + h * (BM * 64) + l * 8192 + tid * 16);
  };
  auto stageB = [&](int b, int h, int kt) {
#pragma unroll
    for (int l = 0; l < LB; ++l)
      gload16(Bs + (long)l * 128 * ldb + kt * 64 + h * 32,
              BL + b * (BN * 128) + h * (BN * 64) + l * 8192 + tid * 16);
  };

  const int aoff = (wr * (BM / 2) + fr) * 64 + ((fq ^ ((fr >> 1) & 3)) << 4);
  const int boff = (wc * (BN / 4) + fr) * 64 + ((fq ^ ((fr >> 1) & 3)) << 4);
  auto ardf = [&](int b, int kk, int m) -> short8 {
    return *(const short8*)(AL + b * (BM * 128) + kk * (BM * 64) + aoff + m * 1024);
  };
  auto brdf = [&](int b, int kk, int n) -> short8 {
    return *(const short8*)(BL + b * (BN * 128) + kk * (BN * 64) + boff + n * 1024);
  };

  // prologue: tile 0 -> buf 0   (order: A-k0, B-k0, A-k1, B-k1)
  stageA(0, 0, 0); stageB(0, 0, 0); stageA(0, 1, 0); stageB(0, 1, 0);

  for (int u = 0; u < nt; ++u) {
    const int cb = u & 1, nb = cb ^ 1;
    const bool pf = (u + 1 < nt);
    lgkm0();                                   // my ds_reads of buf nb serviced
    barrier_();                                // all waves done reading buf nb
    if (pf) { stageA(nb, 0, u + 1); vmwait<V>(); }   // retire tile-u k0 halves
    else    { vmwait<LA + LB>(); }
    barrier_();                                // k-half 0 resident for all
    short8 bfr[NF], af[MF / 2];
#pragma unroll
    for (int n = 0; n < NF; ++n) bfr[n] = brdf(cb, 0, n);
#pragma unroll
    for (int m = 0; m < MF / 2; ++m) af[m] = ardf(cb, 0, m);
    if (pf) stageB(nb, 0, u + 1);
    __builtin_amdgcn_s_setprio(1);
#pragma unroll
    for (int m = 0; m < MF / 2; ++m)
#pragma unroll
      for (int n = 0; n < NF; ++n)
        acc[m][n] = __builtin_amdgcn_mfma_f32_16x16x32_bf16(af[m], bfr[n], acc[m][n], 0, 0, 0);
    __builtin_amdgcn_s_setprio(0);
#pragma unroll
    for (int m = 0; m < MF / 2; ++m) af[m] = ardf(cb, 0, MF / 2 + m);
    if (pf) stageA(nb, 1, u + 1);
    __builtin_amdgcn_s_setprio(1);
#pragma unroll
    for (int m = 0; m < MF / 2; ++m)
#pragma unroll
      for (int n = 0; n < NF; ++n)
        acc[MF / 2 + m][n] =
            __builtin_amdgcn_mfma_f32_16x16x32_bf16(af[m], bfr[n], acc[MF / 2 + m][n], 0, 0, 0);
    __builtin_amdgcn_s_setprio(0);
    if (pf) vmwait<V>(); else vmwait<0>();     // retire tile-u k1 halves
    barrier_();                                // k-half 1 resident for all
#pragma unroll
    for (int n = 0; n < NF; ++n) bfr[n] = brdf(cb, 1, n);
#pragma unroll
    for (int m = 0; m < MF / 2; ++m) af[m] = ardf(cb, 1, m);
    if (pf) stageB(nb, 1, u + 1);
    __builtin_amdgcn_s_setprio(1);
#pragma unroll
    for (int m = 0; m < MF / 2; ++m)
#pragma unroll
      for (int n = 0; n < NF; ++n)
        acc[m][n] = __builtin_amdgcn_mfma_f32_16x16x32_bf16(af[m], bfr[n], acc[m][n], 0, 0, 0);
    __builtin_amdgcn_s_setprio(0);
#pragma unroll
    for (int m = 0; m < MF / 2; ++m) af[m] = ardf(cb, 1, MF / 2 + m);
    __builtin_amdgcn_s_setprio(1);
#pragma unroll
    for (int m = 0; m < MF / 2; ++m)
#pragma unroll
      for (int n = 0; n < NF; ++n)
        acc[MF / 2 + m][n] =
            __builtin_amdgcn_mfma_f32_16x16x32_bf16(af[m], bfr[n], acc[MF / 2 + m][n], 0, 0, 0);
    __builtin_amdgcn_s_setprio(0);
  }

  // C/D layout: col = lane&15, row = (lane>>4)*4 + reg
#pragma unroll
  for (int m = 0; m < MF; ++m) {
    const int row = m0 + wr * (BM / 2) + m * 16 + fq * 4;
#pragma unroll
    for (int n = 0; n < NF; ++n) {
      const int col = n0 + wc * (BN / 4) + n * 16 + fr;
#pragma unroll
      for (int r = 0; r < 4; ++r) {
        float v = acc[m][n][r];
        if constexpr (sizeof(CT) == 2)
          C[(long)(row + r) * ldc + col] = (CT)f2bf(v);
        else
          C[(long)(row + r) * ldc + col] = (CT)v;
      }
    }
  }
}

// Fused Q/K/VT projections: 384 blocks, XCD-swizzled.
__global__ __launch_bounds__(512, 2)
void qkv_gemm(const unsigned short* __restrict__ Xq, const unsigned short* __restrict__ WQT,
              unsigned short* __restrict__ Q,
              const unsigned short* __restrict__ Xk, const unsigned short* __restrict__ WKT,
              unsigned short* __restrict__ Kk,
              const unsigned short* __restrict__ WVT, const unsigned short* __restrict__ Xv,
              unsigned short* __restrict__ VT) {
  const int id = (blockIdx.x & 7) * 48 + (blockIdx.x >> 3);   // 384 % 8 == 0
  const unsigned short *A, *B;
  unsigned short* C;
  int bm, bn, ldc = 1024;
  if (id < 128)      { A = Xq;  B = WQT; C = Q;  bm = id >> 2;        bn = id & 3; }
  else if (id < 256) { int r = id - 128; A = Xk;  B = WKT; C = Kk; bm = r >> 2;  bn = r & 3; }
  else               { int r = id - 256; A = WVT; B = Xv;  C = VT; bm = r >> 5;  bn = r & 31; ldc = 8192; }
  gemm_body<unsigned short, 8, 4>(A, B, C, bm, bn, 1024, 1024, 1024, ldc);
}

// Scores: S_b = Q_b K_b^T (scale in Q); skip above-diagonal 256-tiles.
__global__ __launch_bounds__(512, 2)
void scores_gemm(const unsigned short* __restrict__ Q, const unsigned short* __restrict__ K,
                 unsigned short* __restrict__ S) {
  const int id = (blockIdx.x & 7) * 32 + (blockIdx.x >> 3);   // 256 % 8 == 0
  const int bz = id >> 6, r = id & 63, bm = r >> 3, bn = r & 7;
  if (bn > bm) return;
  gemm_body<unsigned short, 8, 4>(Q + (long)bz * 2048 * 1024, K + (long)bz * 2048 * 1024,
                                  S + (long)bz * 2048 * 2048, bm, bn, 1024, 1024, 1024, 2048);
}

// PV: out_b = P_b V_b; 128x128 tiles (64 KiB LDS -> 2 blocks/CU).
// Heavy+light pairing: block b<256 gets bm=15-(b>>5), b>=256 gets bm=(b-256)>>5;
// round-robin dispatch pairs b and b+256 on the same CU -> K-sum 2176 per CU.
__global__ __launch_bounds__(512, 4)
void pv_gemm(const unsigned short* __restrict__ P, const unsigned short* __restrict__ VT,
             float* __restrict__ O) {
  const int b = blockIdx.x;
  int bm, r;
  if (b < 256) { bm = 15 - (b >> 5); r = b & 31; }
  else         { bm = (b - 256) >> 5; r = b & 31; }
  const int bn = r & 7, bz = r >> 3;
  gemm_body<float, 4, 2>(P + (long)bz * 2048 * 2048, VT + (long)bz * 2048,
                         O + (long)bz * 2048 * 1024, bm, bn, (bm + 1) * 128,
                         2048, 8192, 1024);
}

// ---------------- causal softmax, vectorized, register-resident -------------
__global__ __launch_bounds__(256)
void softmax_causal(unsigned short* __restrict__ P) {
  const int row = blockIdx.x;              // b*2048 + q
  const int q = row & 2047;
  unsigned short* p = P + (long)row * 2048;
  const int nfill = ((q >> 7) + 1) << 7;   // PV reads up to this 128-boundary
  const int tid = threadIdx.x;
  const int lane = tid & 63, wid = tid >> 6;
  const int i0 = tid * 8;
  __shared__ float red[8];

  ushort8 v8 = *(const ushort8*)(p + i0);  // full row; mask below
  float v[8];
  float lmax = -3.0e38f;
#pragma unroll
  for (int j = 0; j < 8; ++j) {
    float f = bf2f(v8[j]);
    f = (i0 + j <= q) ? f : -3.0e38f;
    v[j] = f;
    lmax = fmaxf(lmax, f);
  }
#pragma unroll
  for (int off = 1; off < 64; off <<= 1)
    lmax = fmaxf(lmax, __shfl_xor(lmax, off));
  if (lane == 0) red[wid] = lmax;
  __syncthreads();
  const float mx = fmaxf(fmaxf(red[0], red[1]), fmaxf(red[2], red[3]));

  float lsum = 0.f;
#pragma unroll
  for (int j = 0; j < 8; ++j) {
    float e = __expf(v[j] - mx);           // masked lanes -> exp(-huge) = 0
    v[j] = e;
    lsum += e;
  }
#pragma unroll
  for (int off = 1; off < 64; off <<= 1)
    lsum += __shfl_xor(lsum, off);
  if (lane == 0) red[4 + wid] = lsum;
  __syncthreads();
  const float inv = 1.0f / (red[4] + red[5] + red[6] + red[7]);

  if (i0 < nfill) {
    ushort8 r;
#pragma unroll
    for (int j = 0; j < 8; ++j)
      r[j] = (i0 + j <= q) ? f2bf(v[j] * inv) : (unsigned short)0;
    *(ushort8*)(p + i0) = r;
  }
}

// ---------------------------------------------------------------------------
extern "C" void kernel_launch(void* const* d_in, const int* in_sizes, int n_in,
                              void* d_out, int out_size, void* d_ws, size_t ws_size,
                              hipStream_t stream) {
  const float* Xk = (const float*)d_in[0];
  const float* Xv = (const float*)d_in[1];
  const float* Xq = (const float*)d_in[2];
  const float* WK = (const float*)d_in[3];
  const float* WQ = (const float*)d_in[4];
  const float* WV = (const float*)d_in[5];
  float* out = (float*)d_out;

  unsigned short* ws = (unsigned short*)d_ws;
  const long NE = 8L * 1024 * 1024;          // 8192*1024 elems
  unsigned short* Xqb = ws + 0 * NE;
  unsigned short* Xkb = ws + 1 * NE;
  unsigned short* Xvb = ws + 2 * NE;
  unsigned short* Qb  = ws + 3 * NE;
  unsigned short* Kb  = ws + 4 * NE;
  unsigned short* VTb = ws + 5 * NE;
  unsigned short* WQT = ws + 6 * NE;
  unsigned short* WKT = WQT + 1024 * 1024;
  unsigned short* WVT = WKT + 1024 * 1024;
  unsigned short* Sc  = ws;                  // 2^24 elems, aliases dead Xq+Xk

  dim3 b256(256), b512(512);
  cvt3_bf16<<<12288, b256, 0, stream>>>(Xq, Xk, Xv, Xqb, Xkb, Xvb);
  wtrans3<<<dim3(32, 32, 3), dim3(32, 8), 0, stream>>>(WQ, WK, WV, WQT, WKT, WVT);
  qkv_gemm<<<384, b512, 0, stream>>>(Xqb, WQT, Qb, Xkb, WKT, Kb, WVT, Xvb, VTb);
  scores_gemm<<<256, b512, 0, stream>>>(Qb, Kb, Sc);
  softmax_causal<<<8192, b256, 0, stream>>>(Sc);
  pv_gemm<<<512, b512, 0, stream>>>(Sc, VTb, out);
}

// Round 5
// 157.208 us; speedup vs baseline: 1.6509x; 1.1270x over previous
//
#include <hip/hip_runtime.h>
#include <stdint.h>

// ---------------------------------------------------------------------------
// AttentionHead: out = softmax_causal((Xq WQ)(Xk WK)^T / sqrt(D)) (Xv WV)
// B=4, S=2048, D=1024.  bf16 MFMA, f32 accumulate.
// Round 5: persistent qkvt dispatch — 256 blocks, each runs one full 256^2
// Q-or-K tile THEN one 128x256 VT half-tile (perfect 1.5-T_block balance,
// no half-empty second round).  Softmax skips loads past the causal bdy.
// ---------------------------------------------------------------------------

typedef __attribute__((ext_vector_type(8))) short short8;
typedef __attribute__((ext_vector_type(8))) unsigned short ushort8;
typedef __attribute__((ext_vector_type(4))) float f32x4;

__device__ __forceinline__ unsigned short f2bf(float f) {
  union { float f; unsigned u; } v; v.f = f;
  unsigned u = v.u + 0x7FFFu + ((v.u >> 16) & 1u);   // RNE
  return (unsigned short)(u >> 16);
}
__device__ __forceinline__ float bf2f(unsigned short h) {
  union { unsigned u; float f; } v; v.u = ((unsigned)h) << 16;
  return v.f;
}

__device__ __forceinline__ void gload16(const void* g, void* l) {
  __builtin_amdgcn_global_load_lds(
      (const __attribute__((address_space(1))) unsigned int*)g,
      (__attribute__((address_space(3))) unsigned int*)l, 16, 0, 0);
}

template<int N> __device__ __forceinline__ void vmwait() {
  static_assert(N >= 0 && N <= 8, "vmcnt range");
  if constexpr (N == 0) asm volatile("s_waitcnt vmcnt(0)" ::: "memory");
  else if constexpr (N == 1) asm volatile("s_waitcnt vmcnt(1)" ::: "memory");
  else if constexpr (N == 2) asm volatile("s_waitcnt vmcnt(2)" ::: "memory");
  else if constexpr (N == 3) asm volatile("s_waitcnt vmcnt(3)" ::: "memory");
  else if constexpr (N == 4) asm volatile("s_waitcnt vmcnt(4)" ::: "memory");
  else if constexpr (N == 5) asm volatile("s_waitcnt vmcnt(5)" ::: "memory");
  else if constexpr (N == 6) asm volatile("s_waitcnt vmcnt(6)" ::: "memory");
  else if constexpr (N == 7) asm volatile("s_waitcnt vmcnt(7)" ::: "memory");
  else asm volatile("s_waitcnt vmcnt(8)" ::: "memory");
}
__device__ __forceinline__ void barrier_() { asm volatile("s_barrier" ::: "memory"); }
__device__ __forceinline__ void lgkm0() { asm volatile("s_waitcnt lgkmcnt(0)" ::: "memory"); }

// ---------------- f32 -> bf16 convert, 3 tensors fused ----------------------
__global__ __launch_bounds__(256)
void cvt3_bf16(const float* __restrict__ Xq, const float* __restrict__ Xk,
               const float* __restrict__ Xv,
               unsigned short* __restrict__ Oq, unsigned short* __restrict__ Ok,
               unsigned short* __restrict__ Ov) {
  const int bx = blockIdx.x;
  const int op = bx >> 12, r = bx & 4095;          // 4096 blocks per tensor
  const float* in = op == 0 ? Xq : op == 1 ? Xk : Xv;
  unsigned short* out = op == 0 ? Oq : op == 1 ? Ok : Ov;
  const long i = ((long)r * 256 + threadIdx.x) * 8;
  float4 a = *(const float4*)(in + i);
  float4 b = *(const float4*)(in + i + 4);
  ushort8 rr;
  rr[0] = f2bf(a.x); rr[1] = f2bf(a.y); rr[2] = f2bf(a.z); rr[3] = f2bf(a.w);
  rr[4] = f2bf(b.x); rr[5] = f2bf(b.y); rr[6] = f2bf(b.z); rr[7] = f2bf(b.w);
  *(ushort8*)(out + i) = rr;
}

// ---------------- weight transpose x3: WT[e][k] = W[k][e]*scale -------------
__global__ __launch_bounds__(256)
void wtrans3(const float* __restrict__ WQ, const float* __restrict__ WK,
             const float* __restrict__ WV,
             unsigned short* __restrict__ WQT, unsigned short* __restrict__ WKT,
             unsigned short* __restrict__ WVT) {
  const int z = blockIdx.z;
  const float* W = z == 0 ? WQ : z == 1 ? WK : WV;
  unsigned short* WT = z == 0 ? WQT : z == 1 ? WKT : WVT;
  const float scale = z == 0 ? 0.03125f : 1.0f;    // 1/sqrt(1024) into WQT
  __shared__ float t[32][33];
  const int bk = blockIdx.x * 32, be = blockIdx.y * 32;
  const int tx = threadIdx.x, ty = threadIdx.y;    // (32,8)
#pragma unroll
  for (int j = 0; j < 32; j += 8)
    t[ty + j][tx] = W[(long)(bk + ty + j) * 1024 + (be + tx)];
  __syncthreads();
#pragma unroll
  for (int j = 0; j < 32; j += 8)
    WT[(long)(be + ty + j) * 1024 + (bk + tx)] = f2bf(t[tx][ty + j] * scale);
}

// ---------------- B^T-layout bf16 GEMM, 8-phase, counted vmcnt --------------
// C[m][n] = sum_k A[m][k]*B[n][k].  BM=MF*32, BN=NF*64.  8 waves (2Mx4N).
// LDS (caller-provided): [buf][khalf][row][32]; slot swizzle ^(row>>1)&3.
template<typename CT, int MF, int NF>
__device__ __forceinline__ void gemm_body(const unsigned short* __restrict__ A,
                                          const unsigned short* __restrict__ B,
                                          CT* __restrict__ C,
                                          int bm, int bn, int kmax,
                                          int lda, int ldb, int ldc,
                                          char* AL, char* BL) {
  constexpr int BM = MF * 32, BN = NF * 64;
  constexpr int LA = BM / 128, LB = BN / 128;      // gloads per half-stage
  constexpr int V = 2 * LA + LB;                   // steady-state vmcnt

  const int tid = threadIdx.x;                     // 0..511
  const int lane = tid & 63, wid = tid >> 6;
  const int wr = wid >> 2, wc = wid & 3;           // 2x4 wave grid
  const int fr = lane & 15, fq = lane >> 4;
  const int srow = tid >> 2;                       // staging row 0..127
  const int scol = (((tid & 3) ^ ((tid >> 3) & 3)) << 3);  // pre-swz src col
  const int m0 = bm * BM, n0 = bn * BN;
  const int nt = kmax >> 6;

  f32x4 acc[MF][NF] = {};

  const unsigned short* As = A + (long)(m0 + srow) * lda + scol;
  const unsigned short* Bs = B + (long)(n0 + srow) * ldb + scol;

  auto stageA = [&](int b, int h, int kt) {        // A k-half h of tile kt
#pragma unroll
    for (int l = 0; l < LA; ++l)
      gload16(As + (long)l * 128 * lda + kt * 64 + h * 32,
              AL + b * (BM * 128) + h * (BM * 64) + l * 8192 + tid * 16);
  };
  auto stageB = [&](int b, int h, int kt) {
#pragma unroll
    for (int l = 0; l < LB; ++l)
      gload16(Bs + (long)l * 128 * ldb + kt * 64 + h * 32,
              BL + b * (BN * 128) + h * (BN * 64) + l * 8192 + tid * 16);
  };

  const int aoff = (wr * (BM / 2) + fr) * 64 + ((fq ^ ((fr >> 1) & 3)) << 4);
  const int boff = (wc * (BN / 4) + fr) * 64 + ((fq ^ ((fr >> 1) & 3)) << 4);
  auto ardf = [&](int b, int kk, int m) -> short8 {
    return *(const short8*)(AL + b * (BM * 128) + kk * (BM * 64) + aoff + m * 1024);
  };
  auto brdf = [&](int b, int kk, int n) -> short8 {
    return *(const short8*)(BL + b * (BN * 128) + kk * (BN * 64) + boff + n * 1024);
  };

  // prologue: tile 0 -> buf 0   (order: A-k0, B-k0, A-k1, B-k1)
  stageA(0, 0, 0); stageB(0, 0, 0); stageA(0, 1, 0); stageB(0, 1, 0);

  for (int u = 0; u < nt; ++u) {
    const int cb = u & 1, nb = cb ^ 1;
    const bool pf = (u + 1 < nt);
    lgkm0();                                   // my ds_reads of buf nb serviced
    barrier_();                                // all waves done reading buf nb
    if (pf) { stageA(nb, 0, u + 1); vmwait<V>(); }   // retire tile-u k0 halves
    else    { vmwait<LA + LB>(); }
    barrier_();                                // k-half 0 resident for all
    short8 bfr[NF], af[MF / 2];
#pragma unroll
    for (int n = 0; n < NF; ++n) bfr[n] = brdf(cb, 0, n);
#pragma unroll
    for (int m = 0; m < MF / 2; ++m) af[m] = ardf(cb, 0, m);
    if (pf) stageB(nb, 0, u + 1);
    __builtin_amdgcn_s_setprio(1);
#pragma unroll
    for (int m = 0; m < MF / 2; ++m)
#pragma unroll
      for (int n = 0; n < NF; ++n)
        acc[m][n] = __builtin_amdgcn_mfma_f32_16x16x32_bf16(af[m], bfr[n], acc[m][n], 0, 0, 0);
    __builtin_amdgcn_s_setprio(0);
#pragma unroll
    for (int m = 0; m < MF / 2; ++m) af[m] = ardf(cb, 0, MF / 2 + m);
    if (pf) stageA(nb, 1, u + 1);
    __builtin_amdgcn_s_setprio(1);
#pragma unroll
    for (int m = 0; m < MF / 2; ++m)
#pragma unroll
      for (int n = 0; n < NF; ++n)
        acc[MF / 2 + m][n] =
            __builtin_amdgcn_mfma_f32_16x16x32_bf16(af[m], bfr[n], acc[MF / 2 + m][n], 0, 0, 0);
    __builtin_amdgcn_s_setprio(0);
    if (pf) vmwait<V>(); else vmwait<0>();     // retire tile-u k1 halves
    barrier_();                                // k-half 1 resident for all
#pragma unroll
    for (int n = 0; n < NF; ++n) bfr[n] = brdf(cb, 1, n);
#pragma unroll
    for (int m = 0; m < MF / 2; ++m) af[m] = ardf(cb, 1, m);
    if (pf) stageB(nb, 1, u + 1);
    __builtin_amdgcn_s_setprio(1);
#pragma unroll
    for (int m = 0; m < MF / 2; ++m)
#pragma unroll
      for (int n = 0; n < NF; ++n)
        acc[m][n] = __builtin_amdgcn_mfma_f32_16x16x32_bf16(af[m], bfr[n], acc[m][n], 0, 0, 0);
    __builtin_amdgcn_s_setprio(0);
#pragma unroll
    for (int m = 0; m < MF / 2; ++m) af[m] = ardf(cb, 1, MF / 2 + m);
    __builtin_amdgcn_s_setprio(1);
#pragma unroll
    for (int m = 0; m < MF / 2; ++m)
#pragma unroll
      for (int n = 0; n < NF; ++n)
        acc[MF / 2 + m][n] =
            __builtin_amdgcn_mfma_f32_16x16x32_bf16(af[m], bfr[n], acc[MF / 2 + m][n], 0, 0, 0);
    __builtin_amdgcn_s_setprio(0);
  }

  // C/D layout: col = lane&15, row = (lane>>4)*4 + reg
#pragma unroll
  for (int m = 0; m < MF; ++m) {
    const int row = m0 + wr * (BM / 2) + m * 16 + fq * 4;
#pragma unroll
    for (int n = 0; n < NF; ++n) {
      const int col = n0 + wc * (BN / 4) + n * 16 + fr;
#pragma unroll
      for (int r = 0; r < 4; ++r) {
        float v = acc[m][n][r];
        if constexpr (sizeof(CT) == 2)
          C[(long)(row + r) * ldc + col] = (CT)f2bf(v);
        else
          C[(long)(row + r) * ldc + col] = (CT)v;
      }
    }
  }
}

// Persistent Q/K + VT: 256 blocks.  Each block: one 256^2 Q-or-K tile
// (K=1024), then one 128x256 VT half-tile.  1.5 T_block each, no tail.
__global__ __launch_bounds__(512, 2)
void qkvt_gemm(const unsigned short* __restrict__ Xq, const unsigned short* __restrict__ WQT,
               unsigned short* __restrict__ Q,
               const unsigned short* __restrict__ Xk, const unsigned short* __restrict__ WKT,
               unsigned short* __restrict__ Kk,
               const unsigned short* __restrict__ WVT, const unsigned short* __restrict__ Xv,
               unsigned short* __restrict__ VT) {
  __shared__ __align__(16) char pool[131072];
  const int id = (blockIdx.x & 7) * 32 + (blockIdx.x >> 3);   // 256 % 8 == 0
  // phase 1: Q (id<128) or K projection, 256x256 tile
  if (id < 128)
    gemm_body<unsigned short, 8, 4>(Xq, WQT, Q, id >> 2, id & 3, 1024,
                                    1024, 1024, 1024, pool, pool + 65536);
  else
    gemm_body<unsigned short, 8, 4>(Xk, WKT, Kk, (id - 128) >> 2, id & 3, 1024,
                                    1024, 1024, 1024, pool, pool + 65536);
  __syncthreads();                              // LDS safe to reuse
  // phase 2: VT half-tile 128x256  (VT[1024][8192] = WVT * Xv^T)
  gemm_body<unsigned short, 4, 4>(WVT, Xv, VT, id >> 5, id & 31, 1024,
                                  1024, 1024, 8192, pool, pool + 32768);
}

// Scores: S_b = Q_b K_b^T (scale in Q); skip above-diagonal 256-tiles.
__global__ __launch_bounds__(512, 2)
void scores_gemm(const unsigned short* __restrict__ Q, const unsigned short* __restrict__ K,
                 unsigned short* __restrict__ S) {
  __shared__ __align__(16) char pool[131072];
  const int id = (blockIdx.x & 7) * 32 + (blockIdx.x >> 3);   // 256 % 8 == 0
  const int bz = id >> 6, r = id & 63, bm = r >> 3, bn = r & 7;
  if (bn > bm) return;
  gemm_body<unsigned short, 8, 4>(Q + (long)bz * 2048 * 1024, K + (long)bz * 2048 * 1024,
                                  S + (long)bz * 2048 * 2048, bm, bn, 1024,
                                  1024, 1024, 2048, pool, pool + 65536);
}

// PV: out_b = P_b V_b; 128x128 tiles (64 KiB LDS -> 2 blocks/CU).
// Heavy+light pairing: b<256 gets bm=15-(b>>5), b>=256 gets bm=(b-256)>>5.
__global__ __launch_bounds__(512, 4)
void pv_gemm(const unsigned short* __restrict__ P, const unsigned short* __restrict__ VT,
             float* __restrict__ O) {
  __shared__ __align__(16) char pool[65536];
  const int b = blockIdx.x;
  int bm, r;
  if (b < 256) { bm = 15 - (b >> 5); r = b & 31; }
  else         { bm = (b - 256) >> 5; r = b & 31; }
  const int bn = r & 7, bz = r >> 3;
  gemm_body<float, 4, 2>(P + (long)bz * 2048 * 2048, VT + (long)bz * 2048,
                         O + (long)bz * 2048 * 1024, bm, bn, (bm + 1) * 128,
                         2048, 8192, 1024, pool, pool + 32768);
}

// ---------------- causal softmax, vectorized, register-resident -------------
__global__ __launch_bounds__(256)
void softmax_causal(unsigned short* __restrict__ P) {
  const int row = blockIdx.x;              // b*2048 + q
  const int q = row & 2047;
  unsigned short* p = P + (long)row * 2048;
  const int nfill = ((q >> 7) + 1) << 7;   // PV reads up to this 128-boundary
  const int tid = threadIdx.x;
  const int lane = tid & 63, wid = tid >> 6;
  const int i0 = tid * 8;
  __shared__ float red[8];

  float v[8];
  float lmax = -3.0e38f;
  if (i0 <= q) {                           // skip loads past causal boundary
    ushort8 v8 = *(const ushort8*)(p + i0);
#pragma unroll
    for (int j = 0; j < 8; ++j) {
      float f = bf2f(v8[j]);
      f = (i0 + j <= q) ? f : -3.0e38f;
      v[j] = f;
      lmax = fmaxf(lmax, f);
    }
  } else {
#pragma unroll
    for (int j = 0; j < 8; ++j) v[j] = -3.0e38f;
  }
#pragma unroll
  for (int off = 1; off < 64; off <<= 1)
    lmax = fmaxf(lmax, __shfl_xor(lmax, off));
  if (lane == 0) red[wid] = lmax;
  __syncthreads();
  const float mx = fmaxf(fmaxf(red[0], red[1]), fmaxf(red[2], red[3]));

  float lsum = 0.f;
#pragma unroll
  for (int j = 0; j < 8; ++j) {
    float e = __expf(v[j] - mx);           // masked lanes -> exp(-huge) = 0
    v[j] = e;
    lsum += e;
  }
#pragma unroll
  for (int off = 1; off < 64; off <<= 1)
    lsum += __shfl_xor(lsum, off);
  if (lane == 0) red[4 + wid] = lsum;
  __syncthreads();
  const float inv = 1.0f / (red[4] + red[5] + red[6] + red[7]);

  if (i0 < nfill) {
    ushort8 r;
#pragma unroll
    for (int j = 0; j < 8; ++j)
      r[j] = (i0 + j <= q) ? f2bf(v[j] * inv) : (unsigned short)0;
    *(ushort8*)(p + i0) = r;
  }
}

// ---------------------------------------------------------------------------
extern "C" void kernel_launch(void* const* d_in, const int* in_sizes, int n_in,
                              void* d_out, int out_size, void* d_ws, size_t ws_size,
                              hipStream_t stream) {
  const float* Xk = (const float*)d_in[0];
  const float* Xv = (const float*)d_in[1];
  const float* Xq = (const float*)d_in[2];
  const float* WK = (const float*)d_in[3];
  const float* WQ = (const float*)d_in[4];
  const float* WV = (const float*)d_in[5];
  float* out = (float*)d_out;

  unsigned short* ws = (unsigned short*)d_ws;
  const long NE = 8L * 1024 * 1024;          // 8192*1024 elems
  unsigned short* Xqb = ws + 0 * NE;
  unsigned short* Xkb = ws + 1 * NE;
  unsigned short* Xvb = ws + 2 * NE;
  unsigned short* Qb  = ws + 3 * NE;
  unsigned short* Kb  = ws + 4 * NE;
  unsigned short* VTb = ws + 5 * NE;
  unsigned short* WQT = ws + 6 * NE;
  unsigned short* WKT = WQT + 1024 * 1024;
  unsigned short* WVT = WKT + 1024 * 1024;
  unsigned short* Sc  = ws;                  // 2^24 elems, aliases dead Xq+Xk

  dim3 b256(256), b512(512);
  cvt3_bf16<<<12288, b256, 0, stream>>>(Xq, Xk, Xv, Xqb, Xkb, Xvb);
  wtrans3<<<dim3(32, 32, 3), dim3(32, 8), 0, stream>>>(WQ, WK, WV, WQT, WKT, WVT);
  qkvt_gemm<<<256, b512, 0, stream>>>(Xqb, WQT, Qb, Xkb, WKT, Kb, WVT, Xvb, VTb);
  scores_gemm<<<256, b512, 0, stream>>>(Qb, Kb, Sc);
  softmax_causal<<<8192, b256, 0, stream>>>(Sc);
  pv_gemm<<<512, b512, 0, stream>>>(Sc, VTb, out);
}